// Round 9
// baseline (4618.142 us; speedup 1.0000x reference)
//
#include <hip/hip_runtime.h>
#include <math.h>

// Problem constants
#define BB    256
#define SS    64
#define DD    512
#define HH    8
#define LL    6
#define DFFc  2048
#define LATc  256
#define VVc   16
#define NNODE 64
#define TOK   (BB*SS)   // 16384

typedef __attribute__((ext_vector_type(8))) _Float16 h8v;         // 8 fp16 = 4 VGPR (MFMA A/B frag)
typedef __attribute__((ext_vector_type(4))) float f4v;            // 4 fp32 (MFMA C/D frag)
typedef __attribute__((ext_vector_type(8))) unsigned short u16x8; // 16B LDS write granule

// sinusoidal positional encoding value pe[s][c]
__device__ __forceinline__ float pe_val(int s, int c){
  const float kc = -9.2103403719761836f / 512.0f;   // -ln(10000)/D
  float div = expf((float)(c & ~1) * kc);
  float arg = (float)s * div;
  return (c & 1) ? cosf(arg) : sinf(arg);
}

// --- fp32 -> 2x fp16 split (round-to-nearest; r = a - (float)h0 is exact) ----
// a = h0 + h1 + r with |r| <= 2^-24 |a|.  3-term product (h0b0+h0b1+h1b0).
__device__ __forceinline__ unsigned short hbits(_Float16 h){
  union { _Float16 h; unsigned short u; } x; x.h = h; return x.u;
}
__device__ __forceinline__ void split4h(float4 v, ushort4& h0, ushort4& h1){
  _Float16 a0 = (_Float16)v.x; float r0 = v.x - (float)a0; h0.x = hbits(a0); h1.x = hbits((_Float16)r0);
  _Float16 a1 = (_Float16)v.y; float r1 = v.y - (float)a1; h0.y = hbits(a1); h1.y = hbits((_Float16)r1);
  _Float16 a2 = (_Float16)v.z; float r2 = v.z - (float)a2; h0.z = hbits(a2); h1.z = hbits((_Float16)r2);
  _Float16 a3 = (_Float16)v.w; float r3 = v.w - (float)a3; h0.w = hbits(a3); h1.w = hbits((_Float16)r3);
}
__device__ __forceinline__ u16x8 pack8(ushort4 a, ushort4 b){
  u16x8 r;
  r[0]=a.x; r[1]=a.y; r[2]=a.z; r[3]=a.w;
  r[4]=b.x; r[5]=b.y; r[6]=b.z; r[7]=b.w;
  return r;
}

// async global->LDS, 16B per lane (global addr per-lane, LDS dest = wave-
// uniform base + lane*16).
__device__ __forceinline__ void gload_lds16(const unsigned short* g, unsigned short* l){
  __builtin_amdgcn_global_load_lds(
      (const __attribute__((address_space(1))) unsigned int*)g,
      (__attribute__((address_space(3))) unsigned int*)l,
      16, 0, 0);
}

// ---------------------------------------------------------------------------
// Weight pre-split: W (nk fp32) -> 2 fp16 planes at Wp, Wp+nk. nk%1024==0.
// fp16 2-plane = 4B/elem, byte-identical to fp32 (no FETCH penalty, unlike
// the R2 3x-bf16 attempt). Values identical to in-kernel split4h.
// ---------------------------------------------------------------------------
__global__ __launch_bounds__(256) void presplit_w(
    const float* __restrict__ W, unsigned short* __restrict__ Wp, int nk)
{
  const size_t NK = (size_t)nk;
  const size_t i  = ((size_t)blockIdx.x * 256 + threadIdx.x) * 4;
  float4 v = *(const float4*)(W + i);
  ushort4 h0, h1;
  split4h(v, h0, h1);
  *(ushort4*)&Wp[i]      = h0;
  *(ushort4*)&Wp[NK + i] = h1;
}

// ---------------------------------------------------------------------------
// Embedding
// ---------------------------------------------------------------------------
__global__ __launch_bounds__(128) void emb_kernel(
    const float* __restrict__ ts, const float* __restrict__ te,
    const float* __restrict__ nae, const float* __restrict__ nbe,
    const float* __restrict__ vw, const float* __restrict__ vb,
    float* __restrict__ emb)
{
  const int tok = blockIdx.x;
  const int d   = threadIdx.x;       // 0..127
  float c0  = ts[(size_t)tok*4 + 0];
  float c1  = ts[(size_t)tok*4 + 1];
  float c2  = ts[(size_t)tok*4 + 2];
  float val = ts[(size_t)tok*4 + 3];
  int ct = min(max((int)c0, 0), VVc - 1);
  int na = min(max((int)c1, 0), NNODE - 1);
  int nb = min(max((int)c2, 0), NNODE - 1);
  float* er = emb + (size_t)tok * DD;
  er[d]       = te [ct*128 + d];
  er[128 + d] = nae[na*128 + d];
  er[256 + d] = nbe[nb*128 + d];
  er[384 + d] = val * vw[d] + vb[d];
}

// ---------------------------------------------------------------------------
// MFMA GEMM (BM=BN=128, 4 waves): 2-way fp16 split, 3 MFMA terms.
// fp32 W, split-on-the-fly (CONTROL GROUP vs the DMA variant below).
// Used for qkv, ff1 (large grids). LDS swizzled, 32KB.
// NOTE (R4): no min-waves launch_bounds hint — it spills acc to scratch.
// ---------------------------------------------------------------------------
template<int RELU, int ADDPE>
__global__ __launch_bounds__(256) void gemm_mfma(
    const float* __restrict__ A, const float* __restrict__ W,
    const float* __restrict__ bias, float* __restrict__ Cc,
    int M, int N, int K)
{
  __shared__ __attribute__((aligned(16))) unsigned short Ab[2][128][32];
  __shared__ __attribute__((aligned(16))) unsigned short Bb[2][128][32];
  const int n0 = blockIdx.x * 128;
  const int m0 = blockIdx.y * 128;
  const int t  = threadIdx.x;
  const int lane = t & 63;
  const int wave = t >> 6;           // 0..3
  const int wr = (wave >> 1) * 64;
  const int wc = (wave & 1) * 64;
  const int quad = lane >> 4;
  const int lc   = lane & 15;

  const int srow = t >> 1;
  const int skh  = (t & 1) * 16;

  const int ssw = ((srow ^ (srow >> 2)) & 3);
  const int p0  = (((t & 1) * 2) ^ ssw) * 8;
  const int p1  = ((((t & 1) * 2) ^ ssw) ^ 1) * 8;
  const int fo  = ((quad ^ ((lc ^ (lc >> 2)) & 3))) * 8;

  const float* ap = A + (size_t)(m0 + srow) * K + skh;
  const float* wp = W + (size_t)(n0 + srow) * K + skh;

  f4v acc[4][4];
  #pragma unroll
  for (int i = 0; i < 4; ++i)
    #pragma unroll
    for (int j = 0; j < 4; ++j) acc[i][j] = (f4v){0.f, 0.f, 0.f, 0.f};

  float4 va[4], vb[4];
  #pragma unroll
  for (int q = 0; q < 4; ++q) {
    va[q] = *(const float4*)(ap + q*4);
    vb[q] = *(const float4*)(wp + q*4);
  }

  for (int k0 = 0; k0 < K; k0 += 32) {
    __syncthreads();
    {
      ushort4 h0[4], h1[4];
      #pragma unroll
      for (int q = 0; q < 4; ++q) split4h(va[q], h0[q], h1[q]);
      *(u16x8*)&Ab[0][srow][p0] = pack8(h0[0], h0[1]);
      *(u16x8*)&Ab[0][srow][p1] = pack8(h0[2], h0[3]);
      *(u16x8*)&Ab[1][srow][p0] = pack8(h1[0], h1[1]);
      *(u16x8*)&Ab[1][srow][p1] = pack8(h1[2], h1[3]);
      #pragma unroll
      for (int q = 0; q < 4; ++q) split4h(vb[q], h0[q], h1[q]);
      *(u16x8*)&Bb[0][srow][p0] = pack8(h0[0], h0[1]);
      *(u16x8*)&Bb[0][srow][p1] = pack8(h0[2], h0[3]);
      *(u16x8*)&Bb[1][srow][p0] = pack8(h1[0], h1[1]);
      *(u16x8*)&Bb[1][srow][p1] = pack8(h1[2], h1[3]);
    }
    __syncthreads();
    if (k0 + 32 < K) {
      #pragma unroll
      for (int q = 0; q < 4; ++q) {
        va[q] = *(const float4*)(ap + k0 + 32 + q*4);
        vb[q] = *(const float4*)(wp + k0 + 32 + q*4);
      }
    }
    h8v af[2][4];
    #pragma unroll
    for (int mt = 0; mt < 4; ++mt)
      #pragma unroll
      for (int s = 0; s < 2; ++s)
        af[s][mt] = *(const h8v*)&Ab[s][wr + mt*16 + lc][fo];
    #pragma unroll
    for (int nt = 0; nt < 4; ++nt) {
      h8v b0 = *(const h8v*)&Bb[0][wc + nt*16 + lc][fo];
      h8v b1 = *(const h8v*)&Bb[1][wc + nt*16 + lc][fo];
      #pragma unroll
      for (int mt = 0; mt < 4; ++mt) {
        f4v c = acc[mt][nt];
        c = __builtin_amdgcn_mfma_f32_16x16x32_f16(af[1][mt], b0, c, 0, 0, 0);
        c = __builtin_amdgcn_mfma_f32_16x16x32_f16(af[0][mt], b1, c, 0, 0, 0);
        c = __builtin_amdgcn_mfma_f32_16x16x32_f16(af[0][mt], b0, c, 0, 0, 0);
        acc[mt][nt] = c;
      }
    }
  }
  #pragma unroll
  for (int mt = 0; mt < 4; ++mt)
    #pragma unroll
    for (int nt = 0; nt < 4; ++nt) {
      int col = n0 + wc + nt*16 + lc;
      float bvv = bias ? bias[col] : 0.f;
      #pragma unroll
      for (int r = 0; r < 4; ++r) {
        int row = m0 + wr + mt*16 + quad*4 + r;
        float v = acc[mt][nt][r] + bvv;
        if (RELU)  v = fmaxf(v, 0.f);
        if (ADDPE) v += pe_val(row & (SS - 1), col);
        Cc[(size_t)row * N + col] = v;
      }
    }
}

// ---------------------------------------------------------------------------
// MFMA GEMM (BM=64, BN=128): 3-term fp16 split; B operand PRE-SPLIT (2 fp16
// planes at Wp, Wp+N*K) and staged via global_load_lds (16B/lane DMA): no
// register round-trip, no split VALU, no explicit ds_write on the B path.
// B LDS layout is LINEAR [2][128][32] (DMA writes lane-linear); the b128
// fragment-read pattern on linear layout is bank-balanced at the 8-phase
// floor (verified by bank arithmetic), so no swizzle needed on B.
// A (activations) still fp32, split on the fly with swizzled layout.
// Used for proj, sa_out, ff2, head (N<=512 grids).
// ---------------------------------------------------------------------------
template<int RELU, int ADDPE>
__global__ __launch_bounds__(256) void gemm_mfma64(
    const float* __restrict__ A, const unsigned short* __restrict__ Wp,
    const float* __restrict__ bias, float* __restrict__ Cc,
    int M, int N, int K)
{
  __shared__ __attribute__((aligned(16))) unsigned short Ab[2][64][32];
  __shared__ __attribute__((aligned(16))) unsigned short Bb[2][128][32]; // linear
  const int n0 = blockIdx.x * 128;
  const int m0 = blockIdx.y * 64;
  const int t  = threadIdx.x;
  const int lane = t & 63;
  const int wave = t >> 6;           // 0..3
  const int wr = (wave >> 1) * 32;   // wave row offset (0/32)
  const int wc = (wave & 1) * 64;    // wave col offset (0/64)
  const int quad = lane >> 4;        // 0..3
  const int lc   = lane & 15;

  // A staging: 64 rows x 32 cols, 1 granule (8 floats) per thread per plane
  const int arow = t >> 2;           // 0..63
  const int aq   = t & 3;
  const int pA   = (aq ^ ((arow ^ (arow >> 2)) & 3)) * 8;
  const int fo   = ((quad ^ ((lc ^ (lc >> 2)) & 3))) * 8;  // A reads only

  // B DMA plan: granule g = wave*256 + i*64 + lane of the 1024-granule tile;
  // plane s = g>>9, row r = (g&511)>>2, k-slot p = g&3.
  const size_t NK = (size_t)N * K;
  const unsigned short* srcB0; const unsigned short* srcB1;
  const unsigned short* srcB2; const unsigned short* srcB3;
  {
    int g0 = wave*256 + 0*64 + lane;
    int g1 = wave*256 + 1*64 + lane;
    int g2 = wave*256 + 2*64 + lane;
    int g3 = wave*256 + 3*64 + lane;
    srcB0 = Wp + (size_t)(g0>>9)*NK + (size_t)(n0 + ((g0&511)>>2))*K + (g0&3)*8;
    srcB1 = Wp + (size_t)(g1>>9)*NK + (size_t)(n0 + ((g1&511)>>2))*K + (g1&3)*8;
    srcB2 = Wp + (size_t)(g2>>9)*NK + (size_t)(n0 + ((g2&511)>>2))*K + (g2&3)*8;
    srcB3 = Wp + (size_t)(g3>>9)*NK + (size_t)(n0 + ((g3&511)>>2))*K + (g3&3)*8;
  }
  unsigned short* const bbase = &Bb[0][0][0];
  unsigned short* const dst0 = bbase + (size_t)(wave*256 + 0*64)*8;  // wave-uniform
  unsigned short* const dst1 = bbase + (size_t)(wave*256 + 1*64)*8;
  unsigned short* const dst2 = bbase + (size_t)(wave*256 + 2*64)*8;
  unsigned short* const dst3 = bbase + (size_t)(wave*256 + 3*64)*8;

  const float* ap = A + (size_t)(m0 + arow) * K + aq*8;

  f4v acc[2][4];
  #pragma unroll
  for (int i = 0; i < 2; ++i)
    #pragma unroll
    for (int j = 0; j < 4; ++j) acc[i][j] = (f4v){0.f, 0.f, 0.f, 0.f};

  float4 va[2];
  va[0] = *(const float4*)(ap);
  va[1] = *(const float4*)(ap + 4);

  for (int k0 = 0; k0 < K; k0 += 32) {
    __syncthreads();                 // previous tile fully consumed
    // issue B DMA first so it overlaps the A split VALU
    gload_lds16(srcB0 + k0, dst0);
    gload_lds16(srcB1 + k0, dst1);
    gload_lds16(srcB2 + k0, dst2);
    gload_lds16(srcB3 + k0, dst3);
    {
      ushort4 h0a, h1a, h0b, h1b;
      split4h(va[0], h0a, h1a);
      split4h(va[1], h0b, h1b);
      *(u16x8*)&Ab[0][arow][pA] = pack8(h0a, h0b);
      *(u16x8*)&Ab[1][arow][pA] = pack8(h1a, h1b);
    }
    __syncthreads();                 // compiler drains vmcnt here -> B landed
    if (k0 + 32 < K) {
      va[0] = *(const float4*)(ap + k0 + 32);
      va[1] = *(const float4*)(ap + k0 + 36);
    }
    h8v af[2][2];
    #pragma unroll
    for (int mt = 0; mt < 2; ++mt)
      #pragma unroll
      for (int s = 0; s < 2; ++s)
        af[s][mt] = *(const h8v*)&Ab[s][wr + mt*16 + lc][fo];
    #pragma unroll
    for (int nt = 0; nt < 4; ++nt) {
      h8v b0 = *(const h8v*)&Bb[0][wc + nt*16 + lc][quad*8];
      h8v b1 = *(const h8v*)&Bb[1][wc + nt*16 + lc][quad*8];
      #pragma unroll
      for (int mt = 0; mt < 2; ++mt) {
        f4v c = acc[mt][nt];
        c = __builtin_amdgcn_mfma_f32_16x16x32_f16(af[1][mt], b0, c, 0, 0, 0);
        c = __builtin_amdgcn_mfma_f32_16x16x32_f16(af[0][mt], b1, c, 0, 0, 0);
        c = __builtin_amdgcn_mfma_f32_16x16x32_f16(af[0][mt], b0, c, 0, 0, 0);
        acc[mt][nt] = c;
      }
    }
  }
  #pragma unroll
  for (int mt = 0; mt < 2; ++mt)
    #pragma unroll
    for (int nt = 0; nt < 4; ++nt) {
      int col = n0 + wc + nt*16 + lc;
      float bvv = bias ? bias[col] : 0.f;
      #pragma unroll
      for (int r = 0; r < 4; ++r) {
        int row = m0 + wr + mt*16 + quad*4 + r;
        float v = acc[mt][nt][r] + bvv;
        if (RELU)  v = fmaxf(v, 0.f);
        if (ADDPE) v += pe_val(row & (SS - 1), col);
        Cc[(size_t)row * N + col] = v;
      }
    }
}

// ---------------------------------------------------------------------------
// Small fp32 GEMM, z-batched (latent / cross-attention): BM=BN=64, BK=16.
// blockIdx.z selects the problem: ptr += z*stride. CA chain depends only on
// MEM, so all 6 layers' CA GEMMs are hoisted pre-loop and batched here
// (12 latency-bound 32-block launches -> 2 launches of 192 blocks).
// ---------------------------------------------------------------------------
__global__ __launch_bounds__(256) void gemm64b(
    const float* __restrict__ A, long aStr,
    const float* __restrict__ W, long wStr,
    const float* __restrict__ bias, long bStr,
    float* __restrict__ Cc, long cStr,
    int M, int N, int K)
{
  const int z = blockIdx.z;
  A    += (size_t)z * aStr;
  W    += (size_t)z * wStr;
  bias += (size_t)z * bStr;
  Cc   += (size_t)z * cStr;

  __shared__ float As[16][64];
  __shared__ float Bs[16][64];
  const int n0 = blockIdx.x * 64;
  const int m0 = blockIdx.y * 64;
  const int t  = threadIdx.x;
  const int tx = t & 15;
  const int ty = t >> 4;
  const int sr = t >> 2;
  const int sk = (t & 3) * 4;

  const float* ap = A + (size_t)(m0 + sr) * K + sk;
  const float* wp = W + (size_t)(n0 + sr) * K + sk;

  float acc[4][4];
  #pragma unroll
  for (int i = 0; i < 4; ++i)
    #pragma unroll
    for (int j = 0; j < 4; ++j) acc[i][j] = 0.f;

  float4 a = *(const float4*)ap;
  float4 b = *(const float4*)wp;
  for (int k0 = 0; k0 < K; k0 += 16) {
    __syncthreads();
    As[sk+0][sr]=a.x; As[sk+1][sr]=a.y; As[sk+2][sr]=a.z; As[sk+3][sr]=a.w;
    Bs[sk+0][sr]=b.x; Bs[sk+1][sr]=b.y; Bs[sk+2][sr]=b.z; Bs[sk+3][sr]=b.w;
    __syncthreads();
    if (k0 + 16 < K) {
      a = *(const float4*)(ap + k0 + 16);
      b = *(const float4*)(wp + k0 + 16);
    }
    #pragma unroll
    for (int kk = 0; kk < 16; ++kk) {
      float4 x = *(const float4*)&As[kk][ty*4];
      float4 y = *(const float4*)&Bs[kk][tx*4];
      float xv[4] = {x.x,x.y,x.z,x.w};
      float yv[4] = {y.x,y.y,y.z,y.w};
      #pragma unroll
      for (int i = 0; i < 4; ++i)
        #pragma unroll
        for (int j = 0; j < 4; ++j)
          acc[i][j] += xv[i] * yv[j];
    }
  }
  #pragma unroll
  for (int i = 0; i < 4; ++i) {
    int r = m0 + ty*4 + i;
    float* cp = Cc + (size_t)r * N + n0 + tx*4;
    float4 o;
    o.x = acc[i][0] + (bias ? bias[n0+tx*4+0] : 0.f);
    o.y = acc[i][1] + (bias ? bias[n0+tx*4+1] : 0.f);
    o.z = acc[i][2] + (bias ? bias[n0+tx*4+2] : 0.f);
    o.w = acc[i][3] + (bias ? bias[n0+tx*4+3] : 0.f);
    *(float4*)cp = o;
  }
}

// ---------------------------------------------------------------------------
// Causal self-attention for one (b,h): 64 threads, one query per lane.
// ---------------------------------------------------------------------------
__global__ __launch_bounds__(64) void attn_kernel(
    const float* __restrict__ qkv, float* __restrict__ out)
{
  const int b = blockIdx.x >> 3;
  const int h = blockIdx.x & 7;
  const int lane = threadIdx.x;
  __shared__ float4 ks[64][16];
  __shared__ float4 vs[64][16];
  const float* base = qkv + (size_t)(b*SS + lane) * (3*DD);
  #pragma unroll
  for (int dd = 0; dd < 16; ++dd) {
    ks[lane][dd] = *(const float4*)(base + DD     + h*64 + dd*4);
    vs[lane][dd] = *(const float4*)(base + 2*DD   + h*64 + dd*4);
  }
  float4 q4[16];
  #pragma unroll
  for (int dd = 0; dd < 16; ++dd) q4[dd] = *(const float4*)(base + h*64 + dd*4);
  __syncthreads();

  float s[64];                       // statically indexed -> stays in VGPRs
  float m = -1e30f;
  #pragma unroll
  for (int tk = 0; tk < 64; ++tk) {
    float acc = 0.f;
    #pragma unroll
    for (int dd = 0; dd < 16; ++dd) {
      float4 kv = ks[tk][dd];
      acc += q4[dd].x*kv.x + q4[dd].y*kv.y + q4[dd].z*kv.z + q4[dd].w*kv.w;
    }
    acc *= 0.125f;
    s[tk] = acc;
    if (tk <= lane && acc > m) m = acc;
  }
  float4 o4[16];
  #pragma unroll
  for (int dd = 0; dd < 16; ++dd) { o4[dd].x = 0.f; o4[dd].y = 0.f; o4[dd].z = 0.f; o4[dd].w = 0.f; }
  float l = 0.f;
  #pragma unroll
  for (int tk = 0; tk < 64; ++tk) {
    float w = (tk <= lane) ? expf(s[tk] - m) : 0.f;
    l += w;
    #pragma unroll
    for (int dd = 0; dd < 16; ++dd) {
      float4 vv = vs[tk][dd];
      o4[dd].x += w*vv.x; o4[dd].y += w*vv.y; o4[dd].z += w*vv.z; o4[dd].w += w*vv.w;
    }
  }
  float inv = 1.f / l;
  float* op = out + (size_t)(b*SS + lane) * DD + h*64;
  #pragma unroll
  for (int dd = 0; dd < 16; ++dd) {
    float4 vv; vv.x = o4[dd].x*inv; vv.y = o4[dd].y*inv; vv.z = o4[dd].z*inv; vv.w = o4[dd].w*inv;
    *(float4*)(op + dd*4) = vv;
  }
}

// ---------------------------------------------------------------------------
// x = LayerNorm(x + y) * g + b.  4 tokens per 256-thread block.
// ---------------------------------------------------------------------------
__global__ __launch_bounds__(256) void ln_kernel(
    float* __restrict__ x, const float* __restrict__ y,
    const float* __restrict__ g, const float* __restrict__ b, int ybcast)
{
  const int tok  = blockIdx.x * 4 + (threadIdx.x >> 6);
  const int lane = threadIdx.x & 63;
  float* xr = x + (size_t)tok * DD;
  const float* yr = y + (size_t)(ybcast ? (tok >> 6) : tok) * DD;
  const int c0 = lane * 8;
  float4 v0 = *(const float4*)(xr + c0);
  float4 v1 = *(const float4*)(xr + c0 + 4);
  float4 y0 = *(const float4*)(yr + c0);
  float4 y1 = *(const float4*)(yr + c0 + 4);
  float v[8] = {v0.x+y0.x, v0.y+y0.y, v0.z+y0.z, v0.w+y0.w,
                v1.x+y1.x, v1.y+y1.y, v1.z+y1.z, v1.w+y1.w};
  float sum = 0.f;
  #pragma unroll
  for (int i = 0; i < 8; ++i) sum += v[i];
  #pragma unroll
  for (int off = 32; off; off >>= 1) sum += __shfl_xor(sum, off);
  float mean = sum * (1.f / 512.f);
  float ss = 0.f;
  #pragma unroll
  for (int i = 0; i < 8; ++i) { float d = v[i] - mean; ss += d*d; }
  #pragma unroll
  for (int off = 32; off; off >>= 1) ss += __shfl_xor(ss, off);
  float rinv = 1.f / sqrtf(ss * (1.f / 512.f) + 1e-5f);
  float4 g0 = *(const float4*)(g + c0);
  float4 g1 = *(const float4*)(g + c0 + 4);
  float4 b0 = *(const float4*)(b + c0);
  float4 b1 = *(const float4*)(b + c0 + 4);
  float4 o0, o1;
  o0.x = (v[0]-mean)*rinv*g0.x + b0.x;
  o0.y = (v[1]-mean)*rinv*g0.y + b0.y;
  o0.z = (v[2]-mean)*rinv*g0.z + b0.z;
  o0.w = (v[3]-mean)*rinv*g0.w + b0.w;
  o1.x = (v[4]-mean)*rinv*g1.x + b1.x;
  o1.y = (v[5]-mean)*rinv*g1.y + b1.y;
  o1.z = (v[6]-mean)*rinv*g1.z + b1.z;
  o1.w = (v[7]-mean)*rinv*g1.w + b1.w;
  *(float4*)(xr + c0)     = o0;
  *(float4*)(xr + c0 + 4) = o1;
}

// ---------------------------------------------------------------------------
// Head path A: packed 256x512 weight emitted directly as 2 fp16 planes.
// Rows: [0,16)=type, [16,80)=na, [80,144)=nb(:512), 144=val, [145,256)=pad.
// ---------------------------------------------------------------------------
__global__ __launch_bounds__(128) void build_whead(
    const float* __restrict__ tw, const float* __restrict__ tb,
    const float* __restrict__ nw, const float* __restrict__ nab,
    const float* __restrict__ bw, const float* __restrict__ bbb,
    const float* __restrict__ vw, const float* __restrict__ vb,
    unsigned short* __restrict__ Whp, float* __restrict__ Bh)
{
  const int row = blockIdx.x;         // 0..255
  const int t   = threadIdx.x;        // 0..127
  const float* src = nullptr; float bias = 0.f;
  if      (row < 16)  { src = tw + (size_t)row*512;        bias = tb[row]; }
  else if (row < 80)  { src = nw + (size_t)(row-16)*512;   bias = nab[row-16]; }
  else if (row < 144) { src = bw + (size_t)(row-80)*576;   bias = bbb[row-80]; }
  else if (row == 144){ src = vw;                          bias = vb[0]; }
  const int c = t * 4;
  float4 v;
  if (src) v = *(const float4*)(src + c);
  else { v.x = 0.f; v.y = 0.f; v.z = 0.f; v.w = 0.f; }
  ushort4 h0, h1;
  split4h(v, h0, h1);
  const size_t P = (size_t)256 * 512;
  *(ushort4*)&Whp[(size_t)row*512 + c]     = h0;
  *(ushort4*)&Whp[P + (size_t)row*512 + c] = h1;
  if (t == 0) Bh[row] = bias;
}

__device__ __forceinline__ void argmax64(float& v, int& idx){
  #pragma unroll
  for (int off = 1; off < 64; off <<= 1) {
    float ov = __shfl_xor(v, off);
    int   oi = __shfl_xor(idx, off);
    if (ov > v || (ov == v && oi < idx)) { v = ov; idx = oi; }
  }
}

__global__ __launch_bounds__(64) void head_finalize(
    const float* __restrict__ LG, const float* __restrict__ nb_w,
    const float* __restrict__ gum_a, const float* __restrict__ gum_b,
    float* __restrict__ out)
{
  const int O_NA  = TOK*VVc;
  const int O_NB  = O_NA + TOK*NNODE;
  const int O_VAL = O_NB + TOK*NNODE;
  const int O_SEQ = O_VAL + TOK;
  const int tok  = blockIdx.x;
  const int lane = threadIdx.x;
  const float* lg = LG + (size_t)tok * 256;

  float tl = (lane < VVc) ? lg[lane] : -INFINITY;
  if (lane < VVc) out[(size_t)tok*VVc + lane] = tl;
  float tv = tl; int ti = lane;
  argmax64(tv, ti);

  float nl = lg[16 + lane];
  out[O_NA + (size_t)tok*NNODE + lane] = nl;
  float av = nl + gum_a[(size_t)tok*NNODE + lane];
  int ai = lane;
  argmax64(av, ai);

  float bl = lg[80 + lane] + nb_w[(size_t)lane*576 + 512 + ai];
  out[O_NB + (size_t)tok*NNODE + lane] = bl;
  float mb = (lane == ai) ? -INFINITY : bl;
  mb += gum_b[(size_t)tok*NNODE + lane];
  int bi = lane;
  argmax64(mb, bi);

  if (lane == 0) {
    float value = lg[144];
    out[O_VAL + tok]               = value;
    out[O_SEQ + (size_t)tok*4 + 0] = (float)ti;
    out[O_SEQ + (size_t)tok*4 + 1] = (float)ai;
    out[O_SEQ + (size_t)tok*4 + 2] = (float)bi;
    out[O_SEQ + (size_t)tok*4 + 3] = value;
  }
}

// ---------------------------------------------------------------------------
// Head path B (fallback): one-wave-per-token.
// ---------------------------------------------------------------------------
__device__ __forceinline__ float dot512(const float* __restrict__ xs, const float* __restrict__ w){
  float s = 0.f;
  #pragma unroll 8
  for (int k = 0; k < 512; k += 4) {
    float4 u = *(const float4*)(w + k);
    s += xs[k]*u.x + xs[k+1]*u.y + xs[k+2]*u.z + xs[k+3]*u.w;
  }
  return s;
}

__global__ __launch_bounds__(64) void head_kernel(
    const float* __restrict__ x,
    const float* __restrict__ type_w, const float* __restrict__ type_b,
    const float* __restrict__ na_w,  const float* __restrict__ na_b,
    const float* __restrict__ vw,    const float* __restrict__ vb,
    const float* __restrict__ nb_w,  const float* __restrict__ nb_b,
    const float* __restrict__ gum_a, const float* __restrict__ gum_b,
    float* __restrict__ out)
{
  const int O_NA  = TOK*VVc;
  const int O_NB  = O_NA + TOK*NNODE;
  const int O_VAL = O_NB + TOK*NNODE;
  const int O_SEQ = O_VAL + TOK;
  const int tok  = blockIdx.x;
  const int lane = threadIdx.x;
  __shared__ float xs[512];
  const float* xr = x + (size_t)tok * DD;
  *(float4*)&xs[lane*8]     = *(const float4*)(xr + lane*8);
  *(float4*)&xs[lane*8 + 4] = *(const float4*)(xr + lane*8 + 4);
  __syncthreads();

  float pv = 0.f;
  #pragma unroll
  for (int i = 0; i < 8; ++i) pv += xs[lane*8 + i] * vw[lane*8 + i];
  #pragma unroll
  for (int off = 32; off; off >>= 1) pv += __shfl_xor(pv, off);
  float value = pv + vb[0];

  float tl = -INFINITY;
  if (lane < VVc) {
    tl = type_b[lane] + dot512(xs, type_w + (size_t)lane*512);
    out[(size_t)tok*VVc + lane] = tl;
  }
  float tv = tl; int ti = lane;
  argmax64(tv, ti);

  float nl = na_b[lane] + dot512(xs, na_w + (size_t)lane*512);
  out[O_NA + (size_t)tok*NNODE + lane] = nl;
  float av = nl + gum_a[(size_t)tok*NNODE + lane];
  int ai = lane;
  argmax64(av, ai);

  const float* wr = nb_w + (size_t)lane * 576;
  float bl = nb_b[lane] + dot512(xs, wr) + wr[512 + ai];
  out[O_NB + (size_t)tok*NNODE + lane] = bl;
  float mb = (lane == ai) ? -INFINITY : bl;
  mb += gum_b[(size_t)tok*NNODE + lane];
  int bi = lane;
  argmax64(mb, bi);

  if (lane == 0) {
    out[O_VAL + tok]               = value;
    out[O_SEQ + (size_t)tok*4 + 0] = (float)ti;
    out[O_SEQ + (size_t)tok*4 + 1] = (float)ai;
    out[O_SEQ + (size_t)tok*4 + 2] = (float)bi;
    out[O_SEQ + (size_t)tok*4 + 3] = value;
  }
}

// ---------------------------------------------------------------------------
extern "C" void kernel_launch(void* const* d_in, const int* in_sizes, int n_in,
                              void* d_out, int out_size, void* d_ws, size_t ws_size,
                              hipStream_t stream)
{
  (void)in_sizes; (void)n_in; (void)out_size;
  const float* latent   = (const float*)d_in[0];
  const float* teacher  = (const float*)d_in[1];
  const float* gum_a    = (const float*)d_in[2];
  const float* gum_b    = (const float*)d_in[3];
  const float* type_emb = (const float*)d_in[4];
  const float* nae      = (const float*)d_in[5];
  const float* nbe      = (const float*)d_in[6];
  const float* value_w  = (const float*)d_in[7];
  const float* value_b  = (const float*)d_in[8];
  const float* proj_w   = (const float*)d_in[9];
  const float* proj_b   = (const float*)d_in[10];
  const float* latent_w = (const float*)d_in[11];
  const float* latent_b = (const float*)d_in[12];
  const float* sa_in_w  = (const float*)d_in[13];
  const float* sa_in_b  = (const float*)d_in[14];
  const float* sa_out_w = (const float*)d_in[15];
  const float* sa_out_b = (const float*)d_in[16];
  // d_in[17], d_in[18]: ca_q_w / ca_q_b — dead code: softmax over 1 key == 1
  const float* ca_kv_w  = (const float*)d_in[19];
  const float* ca_kv_b  = (const float*)d_in[20];
  const float* ca_out_w = (const float*)d_in[21];
  const float* ca_out_b = (const float*)d_in[22];
  const float* ff1_w    = (const float*)d_in[23];
  const float* ff1_b    = (const float*)d_in[24];
  const float* ff2_w    = (const float*)d_in[25];
  const float* ff2_b    = (const float*)d_in[26];
  const float* ln1_g    = (const float*)d_in[27];
  const float* ln1_b    = (const float*)d_in[28];
  const float* ln2_g    = (const float*)d_in[29];
  const float* ln2_b    = (const float*)d_in[30];
  const float* ln3_g    = (const float*)d_in[31];
  const float* ln3_b    = (const float*)d_in[32];
  const float* type_w   = (const float*)d_in[33];
  const float* type_b   = (const float*)d_in[34];
  const float* na_w     = (const float*)d_in[35];
  const float* na_b     = (const float*)d_in[36];
  const float* val_w    = (const float*)d_in[37];
  const float* val_b    = (const float*)d_in[38];
  const float* nb_w     = (const float*)d_in[39];
  const float* nb_b     = (const float*)d_in[40];

  // --- Adaptive chunk size: largest C that fits. ---
  // base = X 8388608 + MEM 131072 + CAVall 786432 + CAOall 786432 + WSP 1048576
  int C = 128;
  for (int c = 16384; c >= 128; c >>= 1) {
    size_t need = ((size_t)11141120 + (size_t)3072 * c) * 4;
    if (need <= ws_size) { C = c; break; }
  }
  const int NCH = TOK / C;

  float* ws     = (float*)d_ws;
  float* X      = ws;                            // TOK*512 persistent trunk
  float* U      = X      + (size_t)TOK*DD;       // 2048C union: qkv / ff-hidden / emb / head logits
  float* P1     = U      + (size_t)2048*C;       // C*512 chunk scratch
  float* P2     = P1     + (size_t)C*DD;         // C*512 chunk scratch
  float* MEM    = P2     + (size_t)C*DD;         // 256*512
  float* CAVall = MEM    + (size_t)BB*DD;        // 6 x 256*512 (CA v-proj, all layers)
  float* CAOall = CAVall + (size_t)LL*BB*DD;     // 6 x 256*512 (CA out, all layers)
  unsigned short* WSP = (unsigned short*)(CAOall + (size_t)LL*BB*DD); // 2 fp16 planes, <=1M elems
  float* out = (float*)d_out;

  // x = emb @ proj_w.T + proj_b + PE, chunked: proj weights pre-split once
  presplit_w<<<512*512/1024, 256, 0, stream>>>(proj_w, WSP, 512*512);
  for (int c = 0; c < NCH; ++c) {
    emb_kernel<<<C, 128, 0, stream>>>(teacher + (size_t)c*C*4, type_emb, nae, nbe, value_w, value_b, U);
    gemm_mfma64<0,1><<<dim3(DD/128, C/64), 256, 0, stream>>>(U, WSP, proj_b, X + (size_t)c*C*DD, C, DD, DD);
  }
  // memory = latent @ latent_w.T + latent_b
  gemm64b<<<dim3(DD/64, BB/64, 1), 256, 0, stream>>>(latent, 0, latent_w, 0, latent_b, 0, MEM, 0, BB, DD, LATc);
  // hoisted cross-attention for ALL layers (depends only on MEM)
  gemm64b<<<dim3(DD/64, BB/64, LL), 256, 0, stream>>>(
      MEM, 0, ca_kv_w + (size_t)DD*DD, (long)2*DD*DD, ca_kv_b + DD, (long)2*DD,
      CAVall, (long)BB*DD, BB, DD, DD);
  gemm64b<<<dim3(DD/64, BB/64, LL), 256, 0, stream>>>(
      CAVall, (long)BB*DD, ca_out_w, (long)DD*DD, ca_out_b, (long)DD,
      CAOall, (long)BB*DD, BB, DD, DD);

  for (int l = 0; l < LL; ++l) {
    const float* w_qkv = sa_in_w  + (size_t)l*3*DD*DD;
    const float* b_qkv = sa_in_b  + (size_t)l*3*DD;
    const float* w_so  = sa_out_w + (size_t)l*DD*DD;
    const float* b_so  = sa_out_b + (size_t)l*DD;
    const float* w_f1  = ff1_w    + (size_t)l*DFFc*DD;
    const float* b_f1  = ff1_b    + (size_t)l*DFFc;
    const float* w_f2  = ff2_w    + (size_t)l*DD*DFFc;
    const float* b_f2  = ff2_b    + (size_t)l*DD;

    // self-attention, chunked (sa_out weights pre-split into WSP)
    presplit_w<<<512*512/1024, 256, 0, stream>>>(w_so, WSP, 512*512);
    for (int c = 0; c < NCH; ++c) {
      float* Xc = X + (size_t)c*C*DD;
      gemm_mfma<0,0><<<dim3(3*DD/128, C/128), 256, 0, stream>>>(Xc, w_qkv, b_qkv, U, C, 3*DD, DD);
      attn_kernel<<<(C/SS)*HH, 64, 0, stream>>>(U, P1);
      gemm_mfma64<0,0><<<dim3(DD/128, C/64), 256, 0, stream>>>(P1, WSP, b_so, P2, C, DD, DD);
      ln_kernel<<<C/4, 256, 0, stream>>>(Xc, P2, ln1_g + (size_t)l*DD, ln1_b + (size_t)l*DD, 0);
    }
    // cross-attention result was precomputed: just the residual+LN
    ln_kernel<<<TOK/4, 256, 0, stream>>>(X, CAOall + (size_t)l*BB*DD, ln2_g + (size_t)l*DD, ln2_b + (size_t)l*DD, 1);
    // feed-forward, chunked (ff2 weights pre-split into WSP)
    presplit_w<<<512*2048/1024, 256, 0, stream>>>(w_f2, WSP, 512*2048);
    for (int c = 0; c < NCH; ++c) {
      float* Xc = X + (size_t)c*C*DD;
      gemm_mfma<1,0><<<dim3(DFFc/128, C/128), 256, 0, stream>>>(Xc, w_f1, b_f1, U, C, DFFc, DD);
      gemm_mfma64<0,0><<<dim3(DD/128, C/64), 256, 0, stream>>>(U, WSP, b_f2, P1, C, DD, DFFc);
      ln_kernel<<<C/4, 256, 0, stream>>>(Xc, P1, ln3_g + (size_t)l*DD, ln3_b + (size_t)l*DD, 0);
    }
  }

  // heads
  if (C >= 2048) {
    // head planes into WSP (dead after last ff2); Bh aliases CAVall (dead)
    float* Bh = CAVall;
    float* LG = U;
    build_whead<<<256, 128, 0, stream>>>(type_w, type_b, na_w, na_b, nb_w, nb_b, val_w, val_b, WSP, Bh);
    gemm_mfma64<0,0><<<dim3(256/128, TOK/64), 256, 0, stream>>>(X, WSP, Bh, LG, TOK, 256, 512);
    head_finalize<<<TOK, 64, 0, stream>>>(LG, nb_w, gum_a, gum_b, out);
  } else {
    head_kernel<<<TOK, 64, 0, stream>>>(X, type_w, type_b, na_w, na_b, val_w, val_b,
                                        nb_w, nb_b, gum_a, gum_b, out);
  }
}

// Round 11
// 3647.329 us; speedup vs baseline: 1.2662x; 1.2662x over previous
//
#include <hip/hip_runtime.h>
#include <math.h>

// Problem constants
#define BB    256
#define SS    64
#define DD    512
#define HH    8
#define LL    6
#define DFFc  2048
#define LATc  256
#define VVc   16
#define NNODE 64
#define TOK   (BB*SS)   // 16384

typedef __attribute__((ext_vector_type(8))) _Float16 h8v;         // 8 fp16 = 4 VGPR (MFMA A/B frag)
typedef __attribute__((ext_vector_type(4))) float f4v;            // 4 fp32 (MFMA C/D frag)
typedef __attribute__((ext_vector_type(8))) unsigned short u16x8; // 16B LDS write granule

// sinusoidal positional encoding value pe[s][c]
__device__ __forceinline__ float pe_val(int s, int c){
  const float kc = -9.2103403719761836f / 512.0f;   // -ln(10000)/D
  float div = expf((float)(c & ~1) * kc);
  float arg = (float)s * div;
  return (c & 1) ? cosf(arg) : sinf(arg);
}

// --- fp32 -> 2x fp16 split (round-to-nearest; r = a - (float)h0 is exact) ----
// a = h0 + h1 + r with |r| <= 2^-24 |a|.  3-term product (h0b0+h0b1+h1b0).
__device__ __forceinline__ unsigned short hbits(_Float16 h){
  union { _Float16 h; unsigned short u; } x; x.h = h; return x.u;
}
__device__ __forceinline__ void split4h(float4 v, ushort4& h0, ushort4& h1){
  _Float16 a0 = (_Float16)v.x; float r0 = v.x - (float)a0; h0.x = hbits(a0); h1.x = hbits((_Float16)r0);
  _Float16 a1 = (_Float16)v.y; float r1 = v.y - (float)a1; h0.y = hbits(a1); h1.y = hbits((_Float16)r1);
  _Float16 a2 = (_Float16)v.z; float r2 = v.z - (float)a2; h0.z = hbits(a2); h1.z = hbits((_Float16)r2);
  _Float16 a3 = (_Float16)v.w; float r3 = v.w - (float)a3; h0.w = hbits(a3); h1.w = hbits((_Float16)r3);
}
__device__ __forceinline__ u16x8 pack8(ushort4 a, ushort4 b){
  u16x8 r;
  r[0]=a.x; r[1]=a.y; r[2]=a.z; r[3]=a.w;
  r[4]=b.x; r[5]=b.y; r[6]=b.z; r[7]=b.w;
  return r;
}

// async global->LDS, 16B per lane (global addr per-lane, LDS dest = wave-
// uniform base + lane*16).
__device__ __forceinline__ void gload_lds16(const unsigned short* g, unsigned short* l){
  __builtin_amdgcn_global_load_lds(
      (const __attribute__((address_space(1))) unsigned int*)g,
      (__attribute__((address_space(3))) unsigned int*)l,
      16, 0, 0);
}

// ---------------------------------------------------------------------------
// Weight pre-split: W (nk fp32) -> 2 fp16 planes at Wp, Wp+nk. nk%1024==0.
// ---------------------------------------------------------------------------
__global__ __launch_bounds__(256) void presplit_w(
    const float* __restrict__ W, unsigned short* __restrict__ Wp, int nk)
{
  const size_t NK = (size_t)nk;
  const size_t i  = ((size_t)blockIdx.x * 256 + threadIdx.x) * 4;
  float4 v = *(const float4*)(W + i);
  ushort4 h0, h1;
  split4h(v, h0, h1);
  *(ushort4*)&Wp[i]      = h0;
  *(ushort4*)&Wp[NK + i] = h1;
}

// ---------------------------------------------------------------------------
// Embedding
// ---------------------------------------------------------------------------
__global__ __launch_bounds__(128) void emb_kernel(
    const float* __restrict__ ts, const float* __restrict__ te,
    const float* __restrict__ nae, const float* __restrict__ nbe,
    const float* __restrict__ vw, const float* __restrict__ vb,
    float* __restrict__ emb)
{
  const int tok = blockIdx.x;
  const int d   = threadIdx.x;       // 0..127
  float c0  = ts[(size_t)tok*4 + 0];
  float c1  = ts[(size_t)tok*4 + 1];
  float c2  = ts[(size_t)tok*4 + 2];
  float val = ts[(size_t)tok*4 + 3];
  int ct = min(max((int)c0, 0), VVc - 1);
  int na = min(max((int)c1, 0), NNODE - 1);
  int nb = min(max((int)c2, 0), NNODE - 1);
  float* er = emb + (size_t)tok * DD;
  er[d]       = te [ct*128 + d];
  er[128 + d] = nae[na*128 + d];
  er[256 + d] = nbe[nb*128 + d];
  er[384 + d] = val * vw[d] + vb[d];
}

// ---------------------------------------------------------------------------
// MFMA GEMM (BM=BN=128, 4 waves): 2-way fp16 split, 3 MFMA terms.
// fp32 W, split-on-the-fly. Used for qkv, ff1 (large grids). LDS 32KB.
// NOTE (R4): no min-waves launch_bounds hint — it spills acc to scratch.
// ---------------------------------------------------------------------------
template<int RELU, int ADDPE>
__global__ __launch_bounds__(256) void gemm_mfma(
    const float* __restrict__ A, const float* __restrict__ W,
    const float* __restrict__ bias, float* __restrict__ Cc,
    int M, int N, int K)
{
  __shared__ __attribute__((aligned(16))) unsigned short Ab[2][128][32];
  __shared__ __attribute__((aligned(16))) unsigned short Bb[2][128][32];
  const int n0 = blockIdx.x * 128;
  const int m0 = blockIdx.y * 128;
  const int t  = threadIdx.x;
  const int lane = t & 63;
  const int wave = t >> 6;           // 0..3
  const int wr = (wave >> 1) * 64;
  const int wc = (wave & 1) * 64;
  const int quad = lane >> 4;
  const int lc   = lane & 15;

  const int srow = t >> 1;
  const int skh  = (t & 1) * 16;

  const int ssw = ((srow ^ (srow >> 2)) & 3);
  const int p0  = (((t & 1) * 2) ^ ssw) * 8;
  const int p1  = ((((t & 1) * 2) ^ ssw) ^ 1) * 8;
  const int fo  = ((quad ^ ((lc ^ (lc >> 2)) & 3))) * 8;

  const float* ap = A + (size_t)(m0 + srow) * K + skh;
  const float* wp = W + (size_t)(n0 + srow) * K + skh;

  f4v acc[4][4];
  #pragma unroll
  for (int i = 0; i < 4; ++i)
    #pragma unroll
    for (int j = 0; j < 4; ++j) acc[i][j] = (f4v){0.f, 0.f, 0.f, 0.f};

  float4 va[4], vb[4];
  #pragma unroll
  for (int q = 0; q < 4; ++q) {
    va[q] = *(const float4*)(ap + q*4);
    vb[q] = *(const float4*)(wp + q*4);
  }

  for (int k0 = 0; k0 < K; k0 += 32) {
    __syncthreads();
    {
      ushort4 h0[4], h1[4];
      #pragma unroll
      for (int q = 0; q < 4; ++q) split4h(va[q], h0[q], h1[q]);
      *(u16x8*)&Ab[0][srow][p0] = pack8(h0[0], h0[1]);
      *(u16x8*)&Ab[0][srow][p1] = pack8(h0[2], h0[3]);
      *(u16x8*)&Ab[1][srow][p0] = pack8(h1[0], h1[1]);
      *(u16x8*)&Ab[1][srow][p1] = pack8(h1[2], h1[3]);
      #pragma unroll
      for (int q = 0; q < 4; ++q) split4h(vb[q], h0[q], h1[q]);
      *(u16x8*)&Bb[0][srow][p0] = pack8(h0[0], h0[1]);
      *(u16x8*)&Bb[0][srow][p1] = pack8(h0[2], h0[3]);
      *(u16x8*)&Bb[1][srow][p0] = pack8(h1[0], h1[1]);
      *(u16x8*)&Bb[1][srow][p1] = pack8(h1[2], h1[3]);
    }
    __syncthreads();
    if (k0 + 32 < K) {
      #pragma unroll
      for (int q = 0; q < 4; ++q) {
        va[q] = *(const float4*)(ap + k0 + 32 + q*4);
        vb[q] = *(const float4*)(wp + k0 + 32 + q*4);
      }
    }
    h8v af[2][4];
    #pragma unroll
    for (int mt = 0; mt < 4; ++mt)
      #pragma unroll
      for (int s = 0; s < 2; ++s)
        af[s][mt] = *(const h8v*)&Ab[s][wr + mt*16 + lc][fo];
    #pragma unroll
    for (int nt = 0; nt < 4; ++nt) {
      h8v b0 = *(const h8v*)&Bb[0][wc + nt*16 + lc][fo];
      h8v b1 = *(const h8v*)&Bb[1][wc + nt*16 + lc][fo];
      #pragma unroll
      for (int mt = 0; mt < 4; ++mt) {
        f4v c = acc[mt][nt];
        c = __builtin_amdgcn_mfma_f32_16x16x32_f16(af[1][mt], b0, c, 0, 0, 0);
        c = __builtin_amdgcn_mfma_f32_16x16x32_f16(af[0][mt], b1, c, 0, 0, 0);
        c = __builtin_amdgcn_mfma_f32_16x16x32_f16(af[0][mt], b0, c, 0, 0, 0);
        acc[mt][nt] = c;
      }
    }
  }
  #pragma unroll
  for (int mt = 0; mt < 4; ++mt)
    #pragma unroll
    for (int nt = 0; nt < 4; ++nt) {
      int col = n0 + wc + nt*16 + lc;
      float bvv = bias ? bias[col] : 0.f;
      #pragma unroll
      for (int r = 0; r < 4; ++r) {
        int row = m0 + wr + mt*16 + quad*4 + r;
        float v = acc[mt][nt][r] + bvv;
        if (RELU)  v = fmaxf(v, 0.f);
        if (ADDPE) v += pe_val(row & (SS - 1), col);
        Cc[(size_t)row * N + col] = v;
      }
    }
}

// ---------------------------------------------------------------------------
// MFMA GEMM (BM=64, BN=128): 3-term fp16 split; B operand PRE-SPLIT (2 fp16
// planes at Wp, Wp+N*K) staged via global_load_lds (16B/lane DMA). B LDS
// linear; A fp32 split on the fly, swizzled. proj/sa_out/ff2/head.
// ---------------------------------------------------------------------------
template<int RELU, int ADDPE>
__global__ __launch_bounds__(256) void gemm_mfma64(
    const float* __restrict__ A, const unsigned short* __restrict__ Wp,
    const float* __restrict__ bias, float* __restrict__ Cc,
    int M, int N, int K)
{
  __shared__ __attribute__((aligned(16))) unsigned short Ab[2][64][32];
  __shared__ __attribute__((aligned(16))) unsigned short Bb[2][128][32]; // linear
  const int n0 = blockIdx.x * 128;
  const int m0 = blockIdx.y * 64;
  const int t  = threadIdx.x;
  const int lane = t & 63;
  const int wave = t >> 6;           // 0..3
  const int wr = (wave >> 1) * 32;   // wave row offset (0/32)
  const int wc = (wave & 1) * 64;    // wave col offset (0/64)
  const int quad = lane >> 4;        // 0..3
  const int lc   = lane & 15;

  const int arow = t >> 2;           // 0..63
  const int aq   = t & 3;
  const int pA   = (aq ^ ((arow ^ (arow >> 2)) & 3)) * 8;
  const int fo   = ((quad ^ ((lc ^ (lc >> 2)) & 3))) * 8;  // A reads only

  const size_t NK = (size_t)N * K;
  const unsigned short* srcB0; const unsigned short* srcB1;
  const unsigned short* srcB2; const unsigned short* srcB3;
  {
    int g0 = wave*256 + 0*64 + lane;
    int g1 = wave*256 + 1*64 + lane;
    int g2 = wave*256 + 2*64 + lane;
    int g3 = wave*256 + 3*64 + lane;
    srcB0 = Wp + (size_t)(g0>>9)*NK + (size_t)(n0 + ((g0&511)>>2))*K + (g0&3)*8;
    srcB1 = Wp + (size_t)(g1>>9)*NK + (size_t)(n0 + ((g1&511)>>2))*K + (g1&3)*8;
    srcB2 = Wp + (size_t)(g2>>9)*NK + (size_t)(n0 + ((g2&511)>>2))*K + (g2&3)*8;
    srcB3 = Wp + (size_t)(g3>>9)*NK + (size_t)(n0 + ((g3&511)>>2))*K + (g3&3)*8;
  }
  unsigned short* const bbase = &Bb[0][0][0];
  unsigned short* const dst0 = bbase + (size_t)(wave*256 + 0*64)*8;  // wave-uniform
  unsigned short* const dst1 = bbase + (size_t)(wave*256 + 1*64)*8;
  unsigned short* const dst2 = bbase + (size_t)(wave*256 + 2*64)*8;
  unsigned short* const dst3 = bbase + (size_t)(wave*256 + 3*64)*8;

  const float* ap = A + (size_t)(m0 + arow) * K + aq*8;

  f4v acc[2][4];
  #pragma unroll
  for (int i = 0; i < 2; ++i)
    #pragma unroll
    for (int j = 0; j < 4; ++j) acc[i][j] = (f4v){0.f, 0.f, 0.f, 0.f};

  float4 va[2];
  va[0] = *(const float4*)(ap);
  va[1] = *(const float4*)(ap + 4);

  for (int k0 = 0; k0 < K; k0 += 32) {
    __syncthreads();                 // previous tile fully consumed
    gload_lds16(srcB0 + k0, dst0);
    gload_lds16(srcB1 + k0, dst1);
    gload_lds16(srcB2 + k0, dst2);
    gload_lds16(srcB3 + k0, dst3);
    {
      ushort4 h0a, h1a, h0b, h1b;
      split4h(va[0], h0a, h1a);
      split4h(va[1], h0b, h1b);
      *(u16x8*)&Ab[0][arow][pA] = pack8(h0a, h0b);
      *(u16x8*)&Ab[1][arow][pA] = pack8(h1a, h1b);
    }
    __syncthreads();                 // vmcnt drained -> B landed
    if (k0 + 32 < K) {
      va[0] = *(const float4*)(ap + k0 + 32);
      va[1] = *(const float4*)(ap + k0 + 36);
    }
    h8v af[2][2];
    #pragma unroll
    for (int mt = 0; mt < 2; ++mt)
      #pragma unroll
      for (int s = 0; s < 2; ++s)
        af[s][mt] = *(const h8v*)&Ab[s][wr + mt*16 + lc][fo];
    #pragma unroll
    for (int nt = 0; nt < 4; ++nt) {
      h8v b0 = *(const h8v*)&Bb[0][wc + nt*16 + lc][quad*8];
      h8v b1 = *(const h8v*)&Bb[1][wc + nt*16 + lc][quad*8];
      #pragma unroll
      for (int mt = 0; mt < 2; ++mt) {
        f4v c = acc[mt][nt];
        c = __builtin_amdgcn_mfma_f32_16x16x32_f16(af[1][mt], b0, c, 0, 0, 0);
        c = __builtin_amdgcn_mfma_f32_16x16x32_f16(af[0][mt], b1, c, 0, 0, 0);
        c = __builtin_amdgcn_mfma_f32_16x16x32_f16(af[0][mt], b0, c, 0, 0, 0);
        acc[mt][nt] = c;
      }
    }
  }
  #pragma unroll
  for (int mt = 0; mt < 2; ++mt)
    #pragma unroll
    for (int nt = 0; nt < 4; ++nt) {
      int col = n0 + wc + nt*16 + lc;
      float bvv = bias ? bias[col] : 0.f;
      #pragma unroll
      for (int r = 0; r < 4; ++r) {
        int row = m0 + wr + mt*16 + quad*4 + r;
        float v = acc[mt][nt][r] + bvv;
        if (RELU)  v = fmaxf(v, 0.f);
        if (ADDPE) v += pe_val(row & (SS - 1), col);
        Cc[(size_t)row * N + col] = v;
      }
    }
}

// ---------------------------------------------------------------------------
// Small fp32 GEMM, z-batched (latent / cross-attention): BM=BN=64, BK=16.
// ---------------------------------------------------------------------------
__global__ __launch_bounds__(256) void gemm64b(
    const float* __restrict__ A, long aStr,
    const float* __restrict__ W, long wStr,
    const float* __restrict__ bias, long bStr,
    float* __restrict__ Cc, long cStr,
    int M, int N, int K)
{
  const int z = blockIdx.z;
  A    += (size_t)z * aStr;
  W    += (size_t)z * wStr;
  bias += (size_t)z * bStr;
  Cc   += (size_t)z * cStr;

  __shared__ float As[16][64];
  __shared__ float Bs[16][64];
  const int n0 = blockIdx.x * 64;
  const int m0 = blockIdx.y * 64;
  const int t  = threadIdx.x;
  const int tx = t & 15;
  const int ty = t >> 4;
  const int sr = t >> 2;
  const int sk = (t & 3) * 4;

  const float* ap = A + (size_t)(m0 + sr) * K + sk;
  const float* wp = W + (size_t)(n0 + sr) * K + sk;

  float acc[4][4];
  #pragma unroll
  for (int i = 0; i < 4; ++i)
    #pragma unroll
    for (int j = 0; j < 4; ++j) acc[i][j] = 0.f;

  float4 a = *(const float4*)ap;
  float4 b = *(const float4*)wp;
  for (int k0 = 0; k0 < K; k0 += 16) {
    __syncthreads();
    As[sk+0][sr]=a.x; As[sk+1][sr]=a.y; As[sk+2][sr]=a.z; As[sk+3][sr]=a.w;
    Bs[sk+0][sr]=b.x; Bs[sk+1][sr]=b.y; Bs[sk+2][sr]=b.z; Bs[sk+3][sr]=b.w;
    __syncthreads();
    if (k0 + 16 < K) {
      a = *(const float4*)(ap + k0 + 16);
      b = *(const float4*)(wp + k0 + 16);
    }
    #pragma unroll
    for (int kk = 0; kk < 16; ++kk) {
      float4 x = *(const float4*)&As[kk][ty*4];
      float4 y = *(const float4*)&Bs[kk][tx*4];
      float xv[4] = {x.x,x.y,x.z,x.w};
      float yv[4] = {y.x,y.y,y.z,y.w};
      #pragma unroll
      for (int i = 0; i < 4; ++i)
        #pragma unroll
        for (int j = 0; j < 4; ++j)
          acc[i][j] += xv[i] * yv[j];
    }
  }
  #pragma unroll
  for (int i = 0; i < 4; ++i) {
    int r = m0 + ty*4 + i;
    float* cp = Cc + (size_t)r * N + n0 + tx*4;
    float4 o;
    o.x = acc[i][0] + (bias ? bias[n0+tx*4+0] : 0.f);
    o.y = acc[i][1] + (bias ? bias[n0+tx*4+1] : 0.f);
    o.z = acc[i][2] + (bias ? bias[n0+tx*4+2] : 0.f);
    o.w = acc[i][3] + (bias ? bias[n0+tx*4+3] : 0.f);
    *(float4*)cp = o;
  }
}

// ---------------------------------------------------------------------------
// Causal self-attention for one (b,h): 64 threads, one query per lane.
// v3 (R10): COALESCED cooperative staging. The old per-lane staging (lane =
// token, 6KB stride) made every 16B load instruction touch 64 cache lines —
// 48 such loads/lane left the kernel latency-bound (350us/dispatch, VALUBusy
// 8.8%). Now: 16 passes x {q,k,v}, each pass loads 4 rows x 16 lanes x 16B =
// 4 contiguous 256B segments per instruction (16 lines, 4x fewer; 16x fewer
// lines/byte). Q is staged with +1 float4 row pad (per-lane readback, 8-way
// conflict on 16 reads — negligible); K/V compute reads are wave-uniform
// broadcasts (conflict-free, layout-independent). LDS 49KB -> 3 blocks/CU.
// ---------------------------------------------------------------------------
__global__ __launch_bounds__(64) void attn_kernel(
    const float* __restrict__ qkv, float* __restrict__ out)
{
  const int b = blockIdx.x >> 3;
  const int h = blockIdx.x & 7;
  const int lane = threadIdx.x;
  __shared__ float4 qs[64][17];      // padded: per-lane readback
  __shared__ float4 ks[64][16];
  __shared__ float4 vs[64][16];
  const float* gb = qkv + (size_t)(b*SS) * (3*DD) + h*64;
  {
    const int rsub = lane >> 4;      // 0..3
    const int c4   = lane & 15;      // float4 column
    #pragma unroll
    for (int p = 0; p < 16; ++p) {
      const int row = p*4 + rsub;
      const float* rb = gb + (size_t)row * (3*DD);
      qs[row][c4] = *(const float4*)(rb + c4*4);
      ks[row][c4] = *(const float4*)(rb + DD + c4*4);
      vs[row][c4] = *(const float4*)(rb + 2*DD + c4*4);
    }
  }
  __syncthreads();
  float4 q4[16];
  #pragma unroll
  for (int dd = 0; dd < 16; ++dd) q4[dd] = qs[lane][dd];

  float s[64];                       // statically indexed -> stays in VGPRs
  float m = -1e30f;
  #pragma unroll
  for (int tk = 0; tk < 64; ++tk) {
    float acc = 0.f;
    #pragma unroll
    for (int dd = 0; dd < 16; ++dd) {
      float4 kv = ks[tk][dd];
      acc += q4[dd].x*kv.x + q4[dd].y*kv.y + q4[dd].z*kv.z + q4[dd].w*kv.w;
    }
    acc *= 0.125f;
    s[tk] = acc;
    if (tk <= lane && acc > m) m = acc;
  }
  float4 o4[16];
  #pragma unroll
  for (int dd = 0; dd < 16; ++dd) { o4[dd].x = 0.f; o4[dd].y = 0.f; o4[dd].z = 0.f; o4[dd].w = 0.f; }
  float l = 0.f;
  #pragma unroll
  for (int tk = 0; tk < 64; ++tk) {
    float w = (tk <= lane) ? expf(s[tk] - m) : 0.f;
    l += w;
    #pragma unroll
    for (int dd = 0; dd < 16; ++dd) {
      float4 vv = vs[tk][dd];
      o4[dd].x += w*vv.x; o4[dd].y += w*vv.y; o4[dd].z += w*vv.z; o4[dd].w += w*vv.w;
    }
  }
  float inv = 1.f / l;
  float* op = out + (size_t)(b*SS + lane) * DD + h*64;
  #pragma unroll
  for (int dd = 0; dd < 16; ++dd) {
    float4 vv; vv.x = o4[dd].x*inv; vv.y = o4[dd].y*inv; vv.z = o4[dd].z*inv; vv.w = o4[dd].w*inv;
    *(float4*)(op + dd*4) = vv;
  }
}

// ---------------------------------------------------------------------------
// x = LayerNorm(x + y) * g + b.  4 tokens per 256-thread block.
// ---------------------------------------------------------------------------
__global__ __launch_bounds__(256) void ln_kernel(
    float* __restrict__ x, const float* __restrict__ y,
    const float* __restrict__ g, const float* __restrict__ b, int ybcast)
{
  const int tok  = blockIdx.x * 4 + (threadIdx.x >> 6);
  const int lane = threadIdx.x & 63;
  float* xr = x + (size_t)tok * DD;
  const float* yr = y + (size_t)(ybcast ? (tok >> 6) : tok) * DD;
  const int c0 = lane * 8;
  float4 v0 = *(const float4*)(xr + c0);
  float4 v1 = *(const float4*)(xr + c0 + 4);
  float4 y0 = *(const float4*)(yr + c0);
  float4 y1 = *(const float4*)(yr + c0 + 4);
  float v[8] = {v0.x+y0.x, v0.y+y0.y, v0.z+y0.z, v0.w+y0.w,
                v1.x+y1.x, v1.y+y1.y, v1.z+y1.z, v1.w+y1.w};
  float sum = 0.f;
  #pragma unroll
  for (int i = 0; i < 8; ++i) sum += v[i];
  #pragma unroll
  for (int off = 32; off; off >>= 1) sum += __shfl_xor(sum, off);
  float mean = sum * (1.f / 512.f);
  float ss = 0.f;
  #pragma unroll
  for (int i = 0; i < 8; ++i) { float d = v[i] - mean; ss += d*d; }
  #pragma unroll
  for (int off = 32; off; off >>= 1) ss += __shfl_xor(ss, off);
  float rinv = 1.f / sqrtf(ss * (1.f / 512.f) + 1e-5f);
  float4 g0 = *(const float4*)(g + c0);
  float4 g1 = *(const float4*)(g + c0 + 4);
  float4 b0 = *(const float4*)(b + c0);
  float4 b1 = *(const float4*)(b + c0 + 4);
  float4 o0, o1;
  o0.x = (v[0]-mean)*rinv*g0.x + b0.x;
  o0.y = (v[1]-mean)*rinv*g0.y + b0.y;
  o0.z = (v[2]-mean)*rinv*g0.z + b0.z;
  o0.w = (v[3]-mean)*rinv*g0.w + b0.w;
  o1.x = (v[4]-mean)*rinv*g1.x + b1.x;
  o1.y = (v[5]-mean)*rinv*g1.y + b1.y;
  o1.z = (v[6]-mean)*rinv*g1.z + b1.z;
  o1.w = (v[7]-mean)*rinv*g1.w + b1.w;
  *(float4*)(xr + c0)     = o0;
  *(float4*)(xr + c0 + 4) = o1;
}

// ---------------------------------------------------------------------------
// Head path A: packed 256x512 weight emitted directly as 2 fp16 planes.
// Rows: [0,16)=type, [16,80)=na, [80,144)=nb(:512), 144=val, [145,256)=pad.
// ---------------------------------------------------------------------------
__global__ __launch_bounds__(128) void build_whead(
    const float* __restrict__ tw, const float* __restrict__ tb,
    const float* __restrict__ nw, const float* __restrict__ nab,
    const float* __restrict__ bw, const float* __restrict__ bbb,
    const float* __restrict__ vw, const float* __restrict__ vb,
    unsigned short* __restrict__ Whp, float* __restrict__ Bh)
{
  const int row = blockIdx.x;         // 0..255
  const int t   = threadIdx.x;        // 0..127
  const float* src = nullptr; float bias = 0.f;
  if      (row < 16)  { src = tw + (size_t)row*512;        bias = tb[row]; }
  else if (row < 80)  { src = nw + (size_t)(row-16)*512;   bias = nab[row-16]; }
  else if (row < 144) { src = bw + (size_t)(row-80)*576;   bias = bbb[row-80]; }
  else if (row == 144){ src = vw;                          bias = vb[0]; }
  const int c = t * 4;
  float4 v;
  if (src) v = *(const float4*)(src + c);
  else { v.x = 0.f; v.y = 0.f; v.z = 0.f; v.w = 0.f; }
  ushort4 h0, h1;
  split4h(v, h0, h1);
  const size_t P = (size_t)256 * 512;
  *(ushort4*)&Whp[(size_t)row*512 + c]     = h0;
  *(ushort4*)&Whp[P + (size_t)row*512 + c] = h1;
  if (t == 0) Bh[row] = bias;
}

__device__ __forceinline__ void argmax64(float& v, int& idx){
  #pragma unroll
  for (int off = 1; off < 64; off <<= 1) {
    float ov = __shfl_xor(v, off);
    int   oi = __shfl_xor(idx, off);
    if (ov > v || (ov == v && oi < idx)) { v = ov; idx = oi; }
  }
}

__global__ __launch_bounds__(64) void head_finalize(
    const float* __restrict__ LG, const float* __restrict__ nb_w,
    const float* __restrict__ gum_a, const float* __restrict__ gum_b,
    float* __restrict__ out)
{
  const int O_NA  = TOK*VVc;
  const int O_NB  = O_NA + TOK*NNODE;
  const int O_VAL = O_NB + TOK*NNODE;
  const int O_SEQ = O_VAL + TOK;
  const int tok  = blockIdx.x;
  const int lane = threadIdx.x;
  const float* lg = LG + (size_t)tok * 256;

  float tl = (lane < VVc) ? lg[lane] : -INFINITY;
  if (lane < VVc) out[(size_t)tok*VVc + lane] = tl;
  float tv = tl; int ti = lane;
  argmax64(tv, ti);

  float nl = lg[16 + lane];
  out[O_NA + (size_t)tok*NNODE + lane] = nl;
  float av = nl + gum_a[(size_t)tok*NNODE + lane];
  int ai = lane;
  argmax64(av, ai);

  float bl = lg[80 + lane] + nb_w[(size_t)lane*576 + 512 + ai];
  out[O_NB + (size_t)tok*NNODE + lane] = bl;
  float mb = (lane == ai) ? -INFINITY : bl;
  mb += gum_b[(size_t)tok*NNODE + lane];
  int bi = lane;
  argmax64(mb, bi);

  if (lane == 0) {
    float value = lg[144];
    out[O_VAL + tok]               = value;
    out[O_SEQ + (size_t)tok*4 + 0] = (float)ti;
    out[O_SEQ + (size_t)tok*4 + 1] = (float)ai;
    out[O_SEQ + (size_t)tok*4 + 2] = (float)bi;
    out[O_SEQ + (size_t)tok*4 + 3] = value;
  }
}

// ---------------------------------------------------------------------------
// Head path B (fallback): one-wave-per-token.
// ---------------------------------------------------------------------------
__device__ __forceinline__ float dot512(const float* __restrict__ xs, const float* __restrict__ w){
  float s = 0.f;
  #pragma unroll 8
  for (int k = 0; k < 512; k += 4) {
    float4 u = *(const float4*)(w + k);
    s += xs[k]*u.x + xs[k+1]*u.y + xs[k+2]*u.z + xs[k+3]*u.w;
  }
  return s;
}

__global__ __launch_bounds__(64) void head_kernel(
    const float* __restrict__ x,
    const float* __restrict__ type_w, const float* __restrict__ type_b,
    const float* __restrict__ na_w,  const float* __restrict__ na_b,
    const float* __restrict__ vw,    const float* __restrict__ vb,
    const float* __restrict__ nb_w,  const float* __restrict__ nb_b,
    const float* __restrict__ gum_a, const float* __restrict__ gum_b,
    float* __restrict__ out)
{
  const int O_NA  = TOK*VVc;
  const int O_NB  = O_NA + TOK*NNODE;
  const int O_VAL = O_NB + TOK*NNODE;
  const int O_SEQ = O_VAL + TOK;
  const int tok  = blockIdx.x;
  const int lane = threadIdx.x;
  __shared__ float xs[512];
  const float* xr = x + (size_t)tok * DD;
  *(float4*)&xs[lane*8]     = *(const float4*)(xr + lane*8);
  *(float4*)&xs[lane*8 + 4] = *(const float4*)(xr + lane*8 + 4);
  __syncthreads();

  float pv = 0.f;
  #pragma unroll
  for (int i = 0; i < 8; ++i) pv += xs[lane*8 + i] * vw[lane*8 + i];
  #pragma unroll
  for (int off = 32; off; off >>= 1) pv += __shfl_xor(pv, off);
  float value = pv + vb[0];

  float tl = -INFINITY;
  if (lane < VVc) {
    tl = type_b[lane] + dot512(xs, type_w + (size_t)lane*512);
    out[(size_t)tok*VVc + lane] = tl;
  }
  float tv = tl; int ti = lane;
  argmax64(tv, ti);

  float nl = na_b[lane] + dot512(xs, na_w + (size_t)lane*512);
  out[O_NA + (size_t)tok*NNODE + lane] = nl;
  float av = nl + gum_a[(size_t)tok*NNODE + lane];
  int ai = lane;
  argmax64(av, ai);

  const float* wr = nb_w + (size_t)lane * 576;
  float bl = nb_b[lane] + dot512(xs, wr) + wr[512 + ai];
  out[O_NB + (size_t)tok*NNODE + lane] = bl;
  float mb = (lane == ai) ? -INFINITY : bl;
  mb += gum_b[(size_t)tok*NNODE + lane];
  int bi = lane;
  argmax64(mb, bi);

  if (lane == 0) {
    out[O_VAL + tok]               = value;
    out[O_SEQ + (size_t)tok*4 + 0] = (float)ti;
    out[O_SEQ + (size_t)tok*4 + 1] = (float)ai;
    out[O_SEQ + (size_t)tok*4 + 2] = (float)bi;
    out[O_SEQ + (size_t)tok*4 + 3] = value;
  }
}

// ---------------------------------------------------------------------------
extern "C" void kernel_launch(void* const* d_in, const int* in_sizes, int n_in,
                              void* d_out, int out_size, void* d_ws, size_t ws_size,
                              hipStream_t stream)
{
  (void)in_sizes; (void)n_in; (void)out_size;
  const float* latent   = (const float*)d_in[0];
  const float* teacher  = (const float*)d_in[1];
  const float* gum_a    = (const float*)d_in[2];
  const float* gum_b    = (const float*)d_in[3];
  const float* type_emb = (const float*)d_in[4];
  const float* nae      = (const float*)d_in[5];
  const float* nbe      = (const float*)d_in[6];
  const float* value_w  = (const float*)d_in[7];
  const float* value_b  = (const float*)d_in[8];
  const float* proj_w   = (const float*)d_in[9];
  const float* proj_b   = (const float*)d_in[10];
  const float* latent_w = (const float*)d_in[11];
  const float* latent_b = (const float*)d_in[12];
  const float* sa_in_w  = (const float*)d_in[13];
  const float* sa_in_b  = (const float*)d_in[14];
  const float* sa_out_w = (const float*)d_in[15];
  const float* sa_out_b = (const float*)d_in[16];
  // d_in[17], d_in[18]: ca_q_w / ca_q_b — dead code: softmax over 1 key == 1
  const float* ca_kv_w  = (const float*)d_in[19];
  const float* ca_kv_b  = (const float*)d_in[20];
  const float* ca_out_w = (const float*)d_in[21];
  const float* ca_out_b = (const float*)d_in[22];
  const float* ff1_w    = (const float*)d_in[23];
  const float* ff1_b    = (const float*)d_in[24];
  const float* ff2_w    = (const float*)d_in[25];
  const float* ff2_b    = (const float*)d_in[26];
  const float* ln1_g    = (const float*)d_in[27];
  const float* ln1_b    = (const float*)d_in[28];
  const float* ln2_g    = (const float*)d_in[29];
  const float* ln2_b    = (const float*)d_in[30];
  const float* ln3_g    = (const float*)d_in[31];
  const float* ln3_b    = (const float*)d_in[32];
  const float* type_w   = (const float*)d_in[33];
  const float* type_b   = (const float*)d_in[34];
  const float* na_w     = (const float*)d_in[35];
  const float* na_b     = (const float*)d_in[36];
  const float* val_w    = (const float*)d_in[37];
  const float* val_b    = (const float*)d_in[38];
  const float* nb_w     = (const float*)d_in[39];
  const float* nb_b     = (const float*)d_in[40];

  // --- Adaptive chunk size: largest C that fits. ---
  // base = X 8388608 + MEM 131072 + CAVall 786432 + CAOall 786432 + WSP 1048576
  int C = 128;
  for (int c = 16384; c >= 128; c >>= 1) {
    size_t need = ((size_t)11141120 + (size_t)3072 * c) * 4;
    if (need <= ws_size) { C = c; break; }
  }
  const int NCH = TOK / C;

  float* ws     = (float*)d_ws;
  float* X      = ws;                            // TOK*512 persistent trunk
  float* U      = X      + (size_t)TOK*DD;       // 2048C union: qkv / ff-hidden / emb / head logits
  float* P1     = U      + (size_t)2048*C;       // C*512 chunk scratch
  float* P2     = P1     + (size_t)C*DD;         // C*512 chunk scratch
  float* MEM    = P2     + (size_t)C*DD;         // 256*512
  float* CAVall = MEM    + (size_t)BB*DD;        // 6 x 256*512 (CA v-proj, all layers)
  float* CAOall = CAVall + (size_t)LL*BB*DD;     // 6 x 256*512 (CA out, all layers)
  unsigned short* WSP = (unsigned short*)(CAOall + (size_t)LL*BB*DD); // 2 fp16 planes, <=1M elems
  float* out = (float*)d_out;

  // x = emb @ proj_w.T + proj_b + PE, chunked: proj weights pre-split once
  presplit_w<<<512*512/1024, 256, 0, stream>>>(proj_w, WSP, 512*512);
  for (int c = 0; c < NCH; ++c) {
    emb_kernel<<<C, 128, 0, stream>>>(teacher + (size_t)c*C*4, type_emb, nae, nbe, value_w, value_b, U);
    gemm_mfma64<0,1><<<dim3(DD/128, C/64), 256, 0, stream>>>(U, WSP, proj_b, X + (size_t)c*C*DD, C, DD, DD);
  }
  // memory = latent @ latent_w.T + latent_b
  gemm64b<<<dim3(DD/64, BB/64, 1), 256, 0, stream>>>(latent, 0, latent_w, 0, latent_b, 0, MEM, 0, BB, DD, LATc);
  // hoisted cross-attention for ALL layers (depends only on MEM)
  gemm64b<<<dim3(DD/64, BB/64, LL), 256, 0, stream>>>(
      MEM, 0, ca_kv_w + (size_t)DD*DD, (long)2*DD*DD, ca_kv_b + DD, (long)2*DD,
      CAVall, (long)BB*DD, BB, DD, DD);
  gemm64b<<<dim3(DD/64, BB/64, LL), 256, 0, stream>>>(
      CAVall, (long)BB*DD, ca_out_w, (long)DD*DD, ca_out_b, (long)DD,
      CAOall, (long)BB*DD, BB, DD, DD);

  for (int l = 0; l < LL; ++l) {
    const float* w_qkv = sa_in_w  + (size_t)l*3*DD*DD;
    const float* b_qkv = sa_in_b  + (size_t)l*3*DD;
    const float* w_so  = sa_out_w + (size_t)l*DD*DD;
    const float* b_so  = sa_out_b + (size_t)l*DD;
    const float* w_f1  = ff1_w    + (size_t)l*DFFc*DD;
    const float* b_f1  = ff1_b    + (size_t)l*DFFc;
    const float* w_f2  = ff2_w    + (size_t)l*DD*DFFc;
    const float* b_f2  = ff2_b    + (size_t)l*DD;

    // self-attention, chunked (sa_out weights pre-split into WSP)
    presplit_w<<<512*512/1024, 256, 0, stream>>>(w_so, WSP, 512*512);
    for (int c = 0; c < NCH; ++c) {
      float* Xc = X + (size_t)c*C*DD;
      gemm_mfma<0,0><<<dim3(3*DD/128, C/128), 256, 0, stream>>>(Xc, w_qkv, b_qkv, U, C, 3*DD, DD);
      attn_kernel<<<(C/SS)*HH, 64, 0, stream>>>(U, P1);
      gemm_mfma64<0,0><<<dim3(DD/128, C/64), 256, 0, stream>>>(P1, WSP, b_so, P2, C, DD, DD);
      ln_kernel<<<C/4, 256, 0, stream>>>(Xc, P2, ln1_g + (size_t)l*DD, ln1_b + (size_t)l*DD, 0);
    }
    // cross-attention result was precomputed: just the residual+LN
    ln_kernel<<<TOK/4, 256, 0, stream>>>(X, CAOall + (size_t)l*BB*DD, ln2_g + (size_t)l*DD, ln2_b + (size_t)l*DD, 1);
    // feed-forward, chunked (ff2 weights pre-split into WSP)
    presplit_w<<<512*2048/1024, 256, 0, stream>>>(w_f2, WSP, 512*2048);
    for (int c = 0; c < NCH; ++c) {
      float* Xc = X + (size_t)c*C*DD;
      gemm_mfma<1,0><<<dim3(DFFc/128, C/128), 256, 0, stream>>>(Xc, w_f1, b_f1, U, C, DFFc, DD);
      gemm_mfma64<0,0><<<dim3(DD/128, C/64), 256, 0, stream>>>(U, WSP, b_f2, P1, C, DD, DFFc);
      ln_kernel<<<C/4, 256, 0, stream>>>(Xc, P1, ln3_g + (size_t)l*DD, ln3_b + (size_t)l*DD, 0);
    }
  }

  // heads
  if (C >= 2048) {
    // head planes into WSP (dead after last ff2); Bh aliases CAVall (dead)
    float* Bh = CAVall;
    float* LG = U;
    build_whead<<<256, 128, 0, stream>>>(type_w, type_b, na_w, na_b, nb_w, nb_b, val_w, val_b, WSP, Bh);
    gemm_mfma64<0,0><<<dim3(256/128, TOK/64), 256, 0, stream>>>(X, WSP, Bh, LG, TOK, 256, 512);
    head_finalize<<<TOK, 64, 0, stream>>>(LG, nb_w, gum_a, gum_b, out);
  } else {
    head_kernel<<<TOK, 64, 0, stream>>>(X, type_w, type_b, na_w, na_b, val_w, val_b,
                                        nb_w, nb_b, gum_a, gum_b, out);
  }
}